// Round 1
// baseline (458.042 us; speedup 1.0000x reference)
//
#include <hip/hip_runtime.h>
#include <hip/hip_bf16.h>
#include <cstdint>

// Problem constants
#define NROWS   131072
#define NUNITS  256
#define N4      1024         // 4*UNITS
#define KTOT    512          // INPUT_DIM + UNITS
#define BK      32
#define NKSTEP  16           // KTOT / BK
#define BM      64
#define THREADS 512
#define WSTR    40           // LDS row stride in shorts (32 bf16 + 8 pad -> 80B, 16B aligned)

typedef float f32x4 __attribute__((ext_vector_type(4)));
typedef short bf16x8 __attribute__((ext_vector_type(8)));

__device__ __forceinline__ short f2bf(float x) {
    unsigned u = __float_as_uint(x);
    u += 0x7FFFu + ((u >> 16) & 1u);   // round-to-nearest-even
    return (short)(u >> 16);
}

// W [512][1024] fp32  ->  Wws [16][1024][32] bf16  (per k-step, column-major-within-step,
// 8-contiguous-k per 16B granule: matches the mfma_f32_16x16x32_bf16 B-fragment layout)
__global__ void convert_W_kernel(const float* __restrict__ W, short* __restrict__ Wws) {
    int i = blockIdx.x * 256 + threadIdx.x;       // 0 .. 524287
    int k = i >> 10;
    int c = i & 1023;
    short b = f2bf(W[i]);
    Wws[((size_t)(k >> 5) << 15) + ((size_t)c << 5) + (k & 31)] = b;
}

__global__ void __launch_bounds__(THREADS, 2)
lstm_main_kernel(const float* __restrict__ x, const float* __restrict__ h_prev,
                 const float* __restrict__ c_prev, const float* __restrict__ bias,
                 const float* __restrict__ pi, const float* __restrict__ pf,
                 const float* __restrict__ po, const short* __restrict__ Wws,
                 float* __restrict__ out) {
    __shared__ short Wlds[N4 * WSTR];   // 80 KiB
    __shared__ short Alds[BM * WSTR];   // 5 KiB

    const int t    = threadIdx.x;
    const int lane = t & 63;
    const int w    = t >> 6;            // wave 0..7 -> unit block w*32
    const int row0 = blockIdx.x * BM;

    // ---- staging offsets ----
    const int ar = t >> 3;              // 0..63   (A: one row per thread-octet)
    const int aq = t & 7;               // 0..7    (8 float4 per 32-col row)
    const int a_loff = ar * WSTR + aq * 4;        // shorts

    const int wc0 = t >> 2;             // 0..127  (W: col group)
    const int wq  = t & 3;              // 0..3    (16B granule within 32-k col)

    // ---- fragment read offsets ----
    const int lr = lane & 15;
    const int hi = lane >> 4;
    const int a_rd = lr * WSTR + hi * 8;                 // + mf*16*WSTR
    const int b_rd = (w * 32 + lr) * WSTR + hi * 8;      // + colconst*WSTR

    f32x4 acc[4][8];
    #pragma unroll
    for (int m = 0; m < 4; ++m)
        #pragma unroll
        for (int n = 0; n < 8; ++n)
            acc[m][n] = (f32x4){0.f, 0.f, 0.f, 0.f};

    #pragma unroll 1
    for (int ks = 0; ks < NKSTEP; ++ks) {
        // ---- stage A tile: 64 rows x 32 k, fp32 -> bf16 ----
        const float* asrc = (ks < 8 ? x : h_prev)
                          + (size_t)(row0 + ar) * 256 + (ks & 7) * 32 + aq * 4;
        float4 av = *(const float4*)asrc;
        unsigned p0 = ((unsigned)(unsigned short)f2bf(av.y) << 16) | (unsigned short)f2bf(av.x);
        unsigned p1 = ((unsigned)(unsigned short)f2bf(av.w) << 16) | (unsigned short)f2bf(av.z);
        *(uint2*)(&Alds[a_loff]) = make_uint2(p0, p1);

        // ---- stage W tile: 1024 cols x 32 k bf16 (L2-resident) ----
        const short* wsrc = Wws + ((size_t)ks << 15) + (size_t)wc0 * 32 + wq * 8;
        short* wdst = Wlds + wc0 * WSTR + wq * 8;
        #pragma unroll
        for (int i = 0; i < 8; ++i)
            *(int4*)(wdst + (size_t)i * 128 * WSTR) = *(const int4*)(wsrc + (size_t)i * 128 * 32);

        __syncthreads();

        // ---- MFMA: wave tile 64 rows x 128 cols ----
        bf16x8 af[4];
        #pragma unroll
        for (int m = 0; m < 4; ++m)
            af[m] = *(const bf16x8*)&Alds[a_rd + m * 16 * WSTR];
        #pragma unroll
        for (int n = 0; n < 8; ++n) {
            const int colc = (n >> 1) * 256 + (n & 1) * 16;   // gate*256 + half*16
            bf16x8 bfv = *(const bf16x8*)&Wlds[b_rd + colc * WSTR];
            #pragma unroll
            for (int m = 0; m < 4; ++m)
                acc[m][n] = __builtin_amdgcn_mfma_f32_16x16x32_bf16(af[m], bfv, acc[m][n], 0, 0, 0);
        }
        __syncthreads();
    }

    // ---- fused LSTM epilogue (lane-local: all 4 gates in-register) ----
    const size_t HS = (size_t)NROWS * NUNITS;
    #pragma unroll
    for (int half = 0; half < 2; ++half) {
        const int u = w * 32 + half * 16 + lr;
        const float bi = bias[u],       bfg = bias[256 + u];
        const float bc = bias[512 + u], bo  = bias[768 + u];
        const float ppi = pi[u], ppf = pf[u], ppo = po[u];
        #pragma unroll
        for (int m = 0; m < 4; ++m) {
            #pragma unroll
            for (int r = 0; r < 4; ++r) {
                const int row = row0 + m * 16 + hi * 4 + r;
                const size_t o = (size_t)row * NUNITS + u;
                const float cp = c_prev[o];
                float zi = acc[m][0 + half][r] + bi  + ppi * cp;
                float zf = acc[m][2 + half][r] + bfg + ppf * cp;
                float zc = acc[m][4 + half][r] + bc;
                float zo = acc[m][6 + half][r] + bo  + ppo * cp;
                float ig = 1.f / (1.f + __expf(-zi));
                float fg = 1.f / (1.f + __expf(-zf));
                float og = 1.f / (1.f + __expf(-zo));
                zc = fminf(fmaxf(zc, -30.f), 30.f);
                float e2 = __expf(2.f * zc);
                float ch = (e2 - 1.f) / (e2 + 1.f);
                float c  = fg * cp + ig * ch;
                float ccl = fminf(fmaxf(c, -30.f), 30.f);
                float e3 = __expf(2.f * ccl);
                float th = (e3 - 1.f) / (e3 + 1.f);
                float h  = og * th;
                out[o]           = h;
                out[HS + o]      = h;
                out[2 * HS + o]  = c;
            }
        }
    }
}

extern "C" void kernel_launch(void* const* d_in, const int* in_sizes, int n_in,
                              void* d_out, int out_size, void* d_ws, size_t ws_size,
                              hipStream_t stream) {
    const float* x  = (const float*)d_in[0];
    const float* h  = (const float*)d_in[1];
    const float* c  = (const float*)d_in[2];
    const float* W  = (const float*)d_in[3];
    const float* b  = (const float*)d_in[4];
    const float* pi = (const float*)d_in[5];
    const float* pf = (const float*)d_in[6];
    const float* po = (const float*)d_in[7];
    short* Wws = (short*)d_ws;            // 1 MiB bf16 staging copy of W
    float* out = (float*)d_out;

    hipLaunchKernelGGL(convert_W_kernel, dim3(2048), dim3(256), 0, stream, W, Wws);
    hipLaunchKernelGGL(lstm_main_kernel, dim3(NROWS / BM), dim3(THREADS), 0, stream,
                       x, h, c, b, pi, pf, po, Wws, out);
}

// Round 2
// 334.494 us; speedup vs baseline: 1.3694x; 1.3694x over previous
//
#include <hip/hip_runtime.h>
#include <hip/hip_bf16.h>
#include <cstdint>

// Problem constants
#define NROWS   131072
#define NUNITS  256
#define N4      1024         // 4*UNITS
#define KTOT    512          // INPUT_DIM + UNITS
#define BM      64
#define THREADS 512

typedef float f32x4 __attribute__((ext_vector_type(4)));
typedef short bf16x8 __attribute__((ext_vector_type(8)));

__device__ __forceinline__ short f2bf(float x) {
    unsigned u = __float_as_uint(x);
    u += 0x7FFFu + ((u >> 16) & 1u);   // round-to-nearest-even
    return (short)(u >> 16);
}

// W [512][1024] fp32  ->  Wws [16][1024][32] bf16.
// Per 32-k step, column-major; each column's 32 k-values contiguous (4x 16B
// granules) => a wave's B-fragment load (16 cols x granule) is one fully
// coalesced, contiguous 1 KiB global_load_dwordx4 region. L2-resident (1 MiB).
__global__ void convert_W_kernel(const float* __restrict__ W, short* __restrict__ Wws) {
    int i = blockIdx.x * 256 + threadIdx.x;       // 0 .. 524287
    int k = i >> 10;
    int c = i & 1023;
    short b = f2bf(W[i]);
    Wws[((size_t)(k >> 5) << 15) + ((size_t)c << 5) + (k & 31)] = b;
}

// Main: grid = 4096 blocks = 2048 row-tiles x 2 col-halves.
// Block: 8 waves; wave w owns cols {g*256 + ch*128 + w*16 + lr} for all 4 gates
// => epilogue is fully lane-local. acc[4][4] = 64 VGPRs.
// A (64x32 per kstep) staged in LDS, double-buffered, XOR-swizzled granules:
// granule' = hi ^ ((row>>1)&3) => frag ds_read_b128 is 2-way max (free, m136).
// B-fragments read directly from L2 (no W LDS, no W barriers).
__global__ void __launch_bounds__(THREADS, 4)
lstm_main_kernel(const float* __restrict__ x, const float* __restrict__ h_prev,
                 const float* __restrict__ c_prev, const float* __restrict__ bias,
                 const float* __restrict__ pi, const float* __restrict__ pf,
                 const float* __restrict__ po, const short* __restrict__ Wws,
                 float* __restrict__ out) {
    __shared__ short Alds[2][BM * 32];   // 2 x 4 KiB

    const int t    = threadIdx.x;
    const int lane = t & 63;
    const int w    = t >> 6;             // wave 0..7
    const int rt   = blockIdx.x >> 1;
    const int ch   = blockIdx.x & 1;     // col half (0/1)
    const int row0 = rt * BM;

    const int lr = lane & 15;
    const int hi = lane >> 4;            // 0..3 (k-granule)

    // ---- staging indices: thread -> one float4 of the 64x32 A tile ----
    const int srow = t >> 3;             // 0..63
    const int sh   = t & 7;              // float4 index within 32-k row
    const int sg   = sh >> 1;            // 16B granule 0..3
    const int shalf= sh & 1;
    const int s_lds = srow * 32 + ((sg ^ ((srow >> 1) & 3)) * 8) + shalf * 4; // shorts
    const float* aRowX = x      + (size_t)(row0 + srow) * 256 + sh * 4;
    const float* aRowH = h_prev + (size_t)(row0 + srow) * 256 + sh * 4;

    // ---- fragment read offset (shorts): row=m*16+lr, swizzled granule ----
    const int a_rd = lr * 32 + ((hi ^ ((lr >> 1) & 3)) * 8);   // + m*16*32

    // ---- B-fragment base: col = g*256 + ch*128 + w*16 + lr ----
    const int ucol = ch * 128 + w * 16 + lr;                   // col within gate
    const short* wbase = Wws + (size_t)ucol * 32 + hi * 8;     // + ks*32768 + g*8192

    f32x4 acc[4][4];
    #pragma unroll
    for (int m = 0; m < 4; ++m)
        #pragma unroll
        for (int g = 0; g < 4; ++g)
            acc[m][g] = (f32x4){0.f, 0.f, 0.f, 0.f};

    // ---- stage one k-step (64x32 fp32 -> bf16, swizzled) ----
    auto stage = [&](int kidx, int buf) {
        const float* src = (kidx < 8 ? aRowX : aRowH) + (kidx & 7) * 32;
        float4 av = *(const float4*)src;
        unsigned p0 = ((unsigned)(unsigned short)f2bf(av.y) << 16) | (unsigned short)f2bf(av.x);
        unsigned p1 = ((unsigned)(unsigned short)f2bf(av.w) << 16) | (unsigned short)f2bf(av.z);
        *(uint2*)(&Alds[buf][s_lds]) = make_uint2(p0, p1);
    };

    // ---- compute one k-step from LDS buf + L2 B-frags ----
    auto compute = [&](int ks, int buf) {
        const short* wk = wbase + ((size_t)ks << 15);
        bf16x8 bf[4];
        #pragma unroll
        for (int g = 0; g < 4; ++g)
            bf[g] = *(const bf16x8*)(wk + g * 8192);
        bf16x8 af[4];
        #pragma unroll
        for (int m = 0; m < 4; ++m)
            af[m] = *(const bf16x8*)&Alds[buf][a_rd + m * 16 * 32];
        #pragma unroll
        for (int g = 0; g < 4; ++g)
            #pragma unroll
            for (int m = 0; m < 4; ++m)
                acc[m][g] = __builtin_amdgcn_mfma_f32_16x16x32_bf16(af[m], bf[g], acc[m][g], 0, 0, 0);
    };

    stage(0, 0);
    __syncthreads();

    #pragma unroll 1
    for (int ks2 = 0; ks2 < 8; ++ks2) {
        const int k0 = ks2 * 2;
        stage(k0 + 1, 1);
        compute(k0, 0);
        __syncthreads();
        if (ks2 < 7) stage(k0 + 2, 0);
        compute(k0 + 1, 1);
        __syncthreads();
    }

    // ---- fused LSTM epilogue (lane-local: all 4 gates in acc[m][0..3]) ----
    const size_t HS = (size_t)NROWS * NUNITS;
    const int u = ucol;
    const float bi = bias[u],       bfg = bias[256 + u];
    const float bc = bias[512 + u], bo  = bias[768 + u];
    const float ppi = pi[u], ppf = pf[u], ppo = po[u];
    #pragma unroll
    for (int m = 0; m < 4; ++m) {
        #pragma unroll
        for (int r = 0; r < 4; ++r) {
            const int row = row0 + m * 16 + hi * 4 + r;
            const size_t o = (size_t)row * NUNITS + u;
            const float cp = c_prev[o];
            float zi = acc[m][0][r] + bi  + ppi * cp;
            float zf = acc[m][1][r] + bfg + ppf * cp;
            float zc = acc[m][2][r] + bc;
            float zo = acc[m][3][r] + bo  + ppo * cp;
            float ig = 1.f / (1.f + __expf(-zi));
            float fg = 1.f / (1.f + __expf(-zf));
            float og = 1.f / (1.f + __expf(-zo));
            zc = fminf(fmaxf(zc, -30.f), 30.f);
            float e2 = __expf(2.f * zc);
            float chat = (e2 - 1.f) / (e2 + 1.f);
            float c  = fg * cp + ig * chat;
            float ccl = fminf(fmaxf(c, -30.f), 30.f);
            float e3 = __expf(2.f * ccl);
            float th = (e3 - 1.f) / (e3 + 1.f);
            float h  = og * th;
            out[o]          = h;
            out[HS + o]     = h;
            out[2 * HS + o] = c;
        }
    }
}

extern "C" void kernel_launch(void* const* d_in, const int* in_sizes, int n_in,
                              void* d_out, int out_size, void* d_ws, size_t ws_size,
                              hipStream_t stream) {
    const float* x  = (const float*)d_in[0];
    const float* h  = (const float*)d_in[1];
    const float* c  = (const float*)d_in[2];
    const float* W  = (const float*)d_in[3];
    const float* b  = (const float*)d_in[4];
    const float* pi = (const float*)d_in[5];
    const float* pf = (const float*)d_in[6];
    const float* po = (const float*)d_in[7];
    short* Wws = (short*)d_ws;            // 1 MiB bf16 copy of W in B-frag order
    float* out = (float*)d_out;

    hipLaunchKernelGGL(convert_W_kernel, dim3(2048), dim3(256), 0, stream, W, Wws);
    hipLaunchKernelGGL(lstm_main_kernel, dim3(2 * NROWS / BM), dim3(THREADS), 0, stream,
                       x, h, c, b, pi, pf, po, Wws, out);
}